// Round 1
// baseline (38.642 us; speedup 1.0000x reference)
//
#include <hip/hip_runtime.h>
#include <math.h>

#define NC   16
#define HWSZ (128 * 128)
#define NB   16
#define TOT  (NB * NC * HWSZ)   // 4,194,304 elements per output tensor

typedef float f2 __attribute__((ext_vector_type(2)));

__global__ __launch_bounds__(256) void moe_router_kernel(
    const float* __restrict__ x, const float* __restrict__ noise,
    const float* __restrict__ gp, const float* __restrict__ wnp,
    float* __restrict__ out)
{
    const int t  = blockIdx.x * blockDim.x + threadIdx.x;  // one thread = 2 elems
    const int sp = t << 1;
    const int b  = sp >> 14;            // / HWSZ
    const int hw = sp & (HWSZ - 1);
    const size_t base = (size_t)b * (NC * HWSZ) + hw;

    // per-channel state kept in registers (fully unrolled, compile-time indices)
    float wg[NC][2];
    float wn[NC][2];
    float m1[2]   = {-INFINITY, -INFINITY};
    float m2[2]   = {-INFINITY, -INFINITY};
    float ssum[2] = {0.0f, 0.0f};
    int   amax[2] = {0, 0};

    // Pass 1: load x/noise per channel (coalesced, stride HWSZ), compute
    // wg, wnoise=softplus(x*wnp), Hlogits; online top-2 + softmax sum.
    #pragma unroll
    for (int c = 0; c < NC; ++c) {
        const f2 xv = *reinterpret_cast<const f2*>(x     + base + (size_t)c * HWSZ);
        const f2 nv = *reinterpret_cast<const f2*>(noise + base + (size_t)c * HWSZ);
        const float g = gp[c];
        const float w = wnp[c];
        #pragma unroll
        for (int j = 0; j < 2; ++j) {
            const float wgv = xv[j] * g;
            const float z   = xv[j] * w;
            // stable softplus == logaddexp(z, 0)
            const float spv = fmaxf(z, 0.0f) + log1pf(expf(-fabsf(z)));
            const float hl  = wgv + nv[j] * spv;
            wg[c][j] = wgv;
            wn[c][j] = spv;
            if (hl > m1[j]) {              // strict > : first-occurrence argmax
                ssum[j] = ssum[j] * expf(m1[j] - hl) + 1.0f;  // expf(-inf)=0 on c==0
                m2[j]   = m1[j];
                m1[j]   = hl;
                amax[j] = c;
            } else {
                ssum[j] += expf(hl - m1[j]);
                if (hl > m2[j]) m2[j] = hl;
            }
        }
    }

    // Pass 2: emit G (softmax * onehot(argmax)) and load_loss.
    #pragma unroll
    for (int c = 0; c < NC; ++c) {
        f2 gout, lout;
        #pragma unroll
        for (int j = 0; j < 2; ++j) {
            const bool  top = (c == amax[j]);
            const float mex = top ? m2[j] : m1[j];
            lout[j] = erff((wg[c][j] - mex) / wn[c][j]);
            gout[j] = top ? (1.0f / ssum[j]) : 0.0f;
        }
        *reinterpret_cast<f2*>(out       + base + (size_t)c * HWSZ) = gout;
        *reinterpret_cast<f2*>(out + TOT + base + (size_t)c * HWSZ) = lout;
    }
}

extern "C" void kernel_launch(void* const* d_in, const int* in_sizes, int n_in,
                              void* d_out, int out_size, void* d_ws, size_t ws_size,
                              hipStream_t stream) {
    const float* x     = (const float*)d_in[0];
    const float* noise = (const float*)d_in[1];
    const float* gp    = (const float*)d_in[2];
    const float* wnp   = (const float*)d_in[3];
    float* out = (float*)d_out;

    const int threads = (NB * HWSZ) / 2;   // 131072
    const int block   = 256;
    const int grid    = threads / block;   // 512
    moe_router_kernel<<<grid, block, 0, stream>>>(x, noise, gp, wnp, out);
}

// Round 2
// 18.598 us; speedup vs baseline: 2.0778x; 2.0778x over previous
//
#include <hip/hip_runtime.h>
#include <math.h>

#define NC   16
#define HWSZ (128 * 128)
#define NB   16
#define TOT  (NB * NC * HWSZ)   // 4,194,304 elements per output tensor

__global__ __launch_bounds__(256) void moe_router_kernel(
    const float* __restrict__ x, const float* __restrict__ noise,
    const float* __restrict__ gp, const float* __restrict__ wnp,
    float* __restrict__ out)
{
    const int t  = blockIdx.x * blockDim.x + threadIdx.x;  // one spatial elem
    const int b  = t >> 14;             // / HWSZ
    const int hw = t & (HWSZ - 1);
    const size_t base = (size_t)b * (NC * HWSZ) + hw;

    // Per-channel state in registers (fully unrolled, compile-time indices).
    float wg[NC], wn[NC], hl[NC];
    float m1 = -INFINITY, m2 = -INFINITY;
    int   amax = 0;

    // Pass 1: load (coalesced: 64 lanes x 4B contiguous), compute
    // wg, wnoise = softplus(x*wnp), Hlogits; branchless top-2 + argmax.
    #pragma unroll
    for (int c = 0; c < NC; ++c) {
        const float xv = __builtin_nontemporal_load(x     + base + (size_t)c * HWSZ);
        const float nv = __builtin_nontemporal_load(noise + base + (size_t)c * HWSZ);
        const float wgv = xv * gp[c];
        const float z   = xv * wnp[c];
        // stable softplus == logaddexp(z,0); fast intrinsics (thr 2e-2, err ~1e-6)
        const float spv = fmaxf(z, 0.0f) + __logf(1.0f + __expf(-fabsf(z)));
        const float h   = __builtin_fmaf(nv, spv, wgv);
        wg[c] = wgv;
        wn[c] = spv;
        hl[c] = h;
        amax = (h > m1) ? c : amax;          // strict > : first-occurrence argmax
        m2   = fmaxf(m2, fminf(m1, h));      // branchless top-2
        m1   = fmaxf(m1, h);
    }

    // Pass 2: softmax denominator (no rescale needed, m1 is final max).
    float ssum = 0.0f;
    #pragma unroll
    for (int c = 0; c < NC; ++c)
        ssum += __expf(hl[c] - m1);
    const float ginv = __fdividef(1.0f, ssum);

    // Pass 3: emit G (softmax at argmax, else 0) and load_loss.
    #pragma unroll
    for (int c = 0; c < NC; ++c) {
        const bool  top = (c == amax);
        const float mex = top ? m2 : m1;
        const float ll  = erff(__fdividef(wg[c] - mex, wn[c]));
        __builtin_nontemporal_store(top ? ginv : 0.0f, out + base + (size_t)c * HWSZ);
        __builtin_nontemporal_store(ll, out + TOT + base + (size_t)c * HWSZ);
    }
}

extern "C" void kernel_launch(void* const* d_in, const int* in_sizes, int n_in,
                              void* d_out, int out_size, void* d_ws, size_t ws_size,
                              hipStream_t stream) {
    const float* x     = (const float*)d_in[0];
    const float* noise = (const float*)d_in[1];
    const float* gp    = (const float*)d_in[2];
    const float* wnp   = (const float*)d_in[3];
    float* out = (float*)d_out;

    const int threads = NB * HWSZ;        // 262144 spatial positions
    const int block   = 256;
    const int grid    = threads / block;  // 1024 blocks = 4/CU, 16 waves/CU
    moe_router_kernel<<<grid, block, 0, stream>>>(x, noise, gp, wnp, out);
}

// Round 3
// 17.629 us; speedup vs baseline: 2.1920x; 1.0549x over previous
//
#include <hip/hip_runtime.h>
#include <math.h>

#define NC   16
#define HWSZ (128 * 128)
#define NB   16
#define TOT  (NB * NC * HWSZ)   // 4,194,304 elements per output tensor

// Branchless erf, Abramowitz-Stegun 7.1.26, |err| <= 1.5e-7.
__device__ __forceinline__ float fast_erf(float v) {
    const float ax = fabsf(v);
    const float t  = __fdividef(1.0f, fmaf(0.3275911f, ax, 1.0f));  // rcp
    float p = fmaf(1.061405429f, t, -1.453152027f);
    p = fmaf(p, t,  1.421413741f);
    p = fmaf(p, t, -0.284496736f);
    p = fmaf(p, t,  0.254829592f);
    p *= t;
    const float e = __expf(-v * v);
    const float r = fmaf(-p, e, 1.0f);
    return copysignf(r, v);
}

__global__ __launch_bounds__(256) void moe_router_kernel(
    const float* __restrict__ x, const float* __restrict__ noise,
    const float* __restrict__ gp, const float* __restrict__ wnp,
    float* __restrict__ out)
{
    const int t  = blockIdx.x * blockDim.x + threadIdx.x;  // one spatial elem
    const int b  = t >> 14;             // / HWSZ
    const int hw = t & (HWSZ - 1);
    const size_t base = (size_t)b * (NC * HWSZ) + hw;

    // Per-channel state in registers (fully unrolled, compile-time indices).
    float wg[NC], wn[NC], hl[NC];
    float m1 = -INFINITY, m2 = -INFINITY;
    int   amax = 0;

    // Pass 1: load (coalesced: 64 lanes x 4B contiguous), compute
    // wg, wnoise = softplus(x*wnp), Hlogits; branchless top-2 + argmax.
    #pragma unroll
    for (int c = 0; c < NC; ++c) {
        const float xv = __builtin_nontemporal_load(x     + base + (size_t)c * HWSZ);
        const float nv = __builtin_nontemporal_load(noise + base + (size_t)c * HWSZ);
        const float wgv = xv * gp[c];
        const float z   = xv * wnp[c];
        // stable softplus == logaddexp(z,0); fast intrinsics (thr 2e-2, err ~1e-6)
        const float spv = fmaxf(z, 0.0f) + __logf(1.0f + __expf(-fabsf(z)));
        const float h   = __builtin_fmaf(nv, spv, wgv);
        wg[c] = wgv;
        wn[c] = spv;
        hl[c] = h;
        amax = (h > m1) ? c : amax;          // strict > : first-occurrence argmax
        m2   = fmaxf(m2, fminf(m1, h));      // branchless top-2
        m1   = fmaxf(m1, h);
    }

    // Pass 2: softmax denominator (m1 is the final max, no rescale needed).
    float ssum = 0.0f;
    #pragma unroll
    for (int c = 0; c < NC; ++c)
        ssum += __expf(hl[c] - m1);
    const float ginv = __fdividef(1.0f, ssum);

    // Pass 3: emit G (softmax at argmax, else 0) and load_loss.
    #pragma unroll
    for (int c = 0; c < NC; ++c) {
        const bool  top = (c == amax);
        const float mex = top ? m2 : m1;
        const float ll  = fast_erf(__fdividef(wg[c] - mex, wn[c]));
        __builtin_nontemporal_store(top ? ginv : 0.0f, out + base + (size_t)c * HWSZ);
        __builtin_nontemporal_store(ll, out + TOT + base + (size_t)c * HWSZ);
    }
}

extern "C" void kernel_launch(void* const* d_in, const int* in_sizes, int n_in,
                              void* d_out, int out_size, void* d_ws, size_t ws_size,
                              hipStream_t stream) {
    const float* x     = (const float*)d_in[0];
    const float* noise = (const float*)d_in[1];
    const float* gp    = (const float*)d_in[2];
    const float* wnp   = (const float*)d_in[3];
    float* out = (float*)d_out;

    const int threads = NB * HWSZ;        // 262144 spatial positions
    const int block   = 256;
    const int grid    = threads / block;  // 1024 blocks, 16 waves/CU
    moe_router_kernel<<<grid, block, 0, stream>>>(x, noise, gp, wnp, out);
}